// Round 2
// baseline (1065.288 us; speedup 1.0000x reference)
//
#include <hip/hip_runtime.h>
#include <math.h>

#define AS1 __attribute__((address_space(1)))
#define AS3 __attribute__((address_space(3)))

typedef short bf16x8 __attribute__((ext_vector_type(8)));
typedef short s16x4  __attribute__((ext_vector_type(4)));
typedef float f32x4  __attribute__((ext_vector_type(4)));

#define MFMA(a,b,c) __builtin_amdgcn_mfma_f32_16x16x32_bf16((a),(b),(c),0,0,0)

__device__ __forceinline__ short f2bf(float f) {
  union { float f; unsigned u; } v; v.f = f;
  unsigned r = v.u + 0x7FFFu + ((v.u >> 16) & 1u);
  return (short)(r >> 16);
}

__device__ __forceinline__ void gload16(const void* g, void* l) {
  __builtin_amdgcn_global_load_lds((const AS1 void*)g, (AS3 void*)l, 16, 0, 0);
}

// ---------------- transpose + fp32->bf16 convert: out[c][r] = in[r][c] ----------------
__global__ __launch_bounds__(256) void k_transpose_cvt(
    const float* __restrict__ in, short* __restrict__ out, int R, int C) {
  __shared__ float t[64][65];
  int c0 = blockIdx.x * 64, r0 = blockIdx.y * 64;
  int tx = threadIdx.x & 63, ty = threadIdx.x >> 6;
  for (int r = ty; r < 64; r += 4)
    t[r][tx] = in[(size_t)(r0 + r) * C + c0 + tx];
  __syncthreads();
  for (int c = ty; c < 64; c += 4)
    out[(size_t)(c0 + c) * R + r0 + tx] = f2bf(t[tx][c]);
}

// ---------------- conditioning: h{1,2} = silu(z @ h{1,2}w + b) ----------------
__global__ __launch_bounds__(256) void k_cond_h(
    const float* __restrict__ z,
    const float* __restrict__ h1w, const float* __restrict__ h1b,
    const float* __restrict__ h2w, const float* __restrict__ h2b,
    float* __restrict__ hbuf) {
  int dl = threadIdx.x & 63, kq = threadIdx.x >> 6;
  int d = blockIdx.x * 64 + dl;
  int b = blockIdx.y, sel = blockIdx.z;
  const float* W = (sel ? h2w : h1w) + (size_t)(kq * 256) * 1024 + d;
  const float* zr = z + b * 1024 + kq * 256;
  float acc = 0.f;
  for (int i = 0; i < 256; ++i) acc = fmaf(zr[i], W[(size_t)i * 1024], acc);
  __shared__ float red[256];
  red[threadIdx.x] = acc;
  __syncthreads();
  if (kq == 0) {
    float v = red[dl] + red[dl + 64] + red[dl + 128] + red[dl + 192];
    v += (sel ? h2b : h1b)[d];
    hbuf[(size_t)(sel * 8 + b) * 1024 + d] = v / (1.f + expf(-v));
  }
}

// scale1/offset1/scale2/offset2 = h @ W + b  (sel = blockIdx.z in 0..3)
__global__ __launch_bounds__(256) void k_cond_so(
    const float* __restrict__ hbuf,
    const float* __restrict__ g1w, const float* __restrict__ g1b,
    const float* __restrict__ be1w, const float* __restrict__ be1b,
    const float* __restrict__ g2w, const float* __restrict__ g2b,
    const float* __restrict__ be2w, const float* __restrict__ be2b,
    float* __restrict__ so) {
  int dl = threadIdx.x & 63, kq = threadIdx.x >> 6;
  int d = blockIdx.x * 64 + dl;
  int b = blockIdx.y, sel = blockIdx.z;
  const float* W = sel == 0 ? g1w : sel == 1 ? be1w : sel == 2 ? g2w : be2w;
  const float* bias = sel == 0 ? g1b : sel == 1 ? be1b : sel == 2 ? g2b : be2b;
  const float* hr = hbuf + (size_t)((sel >> 1) * 8 + b) * 1024 + kq * 256;
  const float* Wp = W + (size_t)(kq * 256) * 1024 + d;
  float acc = 0.f;
  for (int i = 0; i < 256; ++i) acc = fmaf(hr[i], Wp[(size_t)i * 1024], acc);
  __shared__ float red[256];
  red[threadIdx.x] = acc;
  __syncthreads();
  if (kq == 0) {
    float v = red[dl] + red[dl + 64] + red[dl + 128] + red[dl + 192] + bias[d];
    so[(size_t)(sel * 8 + b) * 1024 + d] = v;
  }
}

// ---------------- adaLN: xout(bf16) = norm(xin)*scale + offset ----------------
__global__ __launch_bounds__(256) void k_adaln(
    const float* __restrict__ xin, const float* __restrict__ so,
    int which, short* __restrict__ xout) {
  int row = blockIdx.x;
  int b = row >> 11;
  const float4* xr = (const float4*)(xin + (size_t)row * 1024);
  float4 v = xr[threadIdx.x];
  float s = v.x + v.y + v.z + v.w;
  float sq = v.x * v.x + v.y * v.y + v.z * v.z + v.w * v.w;
#pragma unroll
  for (int o = 32; o >= 1; o >>= 1) {
    s += __shfl_xor(s, o, 64);
    sq += __shfl_xor(sq, o, 64);
  }
  __shared__ float red[8];
  int wid = threadIdx.x >> 6;
  if ((threadIdx.x & 63) == 0) { red[wid] = s; red[4 + wid] = sq; }
  __syncthreads();
  s = red[0] + red[1] + red[2] + red[3];
  sq = red[4] + red[5] + red[6] + red[7];
  float mean = s * (1.f / 1024.f);
  float var = sq * (1.f / 1024.f) - mean * mean;
  float rstd = rsqrtf(var + 1e-6f);
  const float4* scp = (const float4*)(so + (size_t)(which * 2) * 8192 + b * 1024);
  const float4* ofp = (const float4*)(so + (size_t)(which * 2 + 1) * 8192 + b * 1024);
  float4 sc = scp[threadIdx.x], of = ofp[threadIdx.x];
  s16x4 o;
  o[0] = f2bf((v.x - mean) * rstd * sc.x + of.x);
  o[1] = f2bf((v.y - mean) * rstd * sc.y + of.y);
  o[2] = f2bf((v.z - mean) * rstd * sc.z + of.z);
  o[3] = f2bf((v.w - mean) * rstd * sc.w + of.w);
  *(s16x4*)(xout + (size_t)row * 1024 + threadIdx.x * 4) = o;
}

// ---------------- generic 128x128 MFMA GEMM, A[M,K] @ BT[N,K]^T ----------------
enum { EPI_QKV = 0, EPI_KP = 1, EPI_VPT = 2, EPI_RESID = 3, EPI_GELU = 4 };

template <int EPI>
__global__ __launch_bounds__(256) void k_gemm(
    const short* __restrict__ A, long sA, int lda,
    const short* __restrict__ BT, long sBT, int ldbt,
    int Kd,
    short* __restrict__ o0, short* __restrict__ o1, short* __restrict__ o2,
    const float* __restrict__ b0, const float* __restrict__ b1,
    const float* __restrict__ b2,
    const float* __restrict__ resid, float* __restrict__ fo, long sC) {
  int t = threadIdx.x, lane = t & 63, wid = t >> 6;
  int wr = wid >> 1, wc = wid & 1;
  int n0 = blockIdx.x * 128, m0 = blockIdx.y * 128, bz = blockIdx.z;
  const short* Ab = A + (long)bz * sA;
  const short* Bb = BT + (long)bz * sBT;
  __shared__ short lds[8192];  // A tile [128][32] then BT tile [128][32]
  const short* gA = Ab + (long)(m0 + (t >> 2)) * lda + (t & 3) * 8;
  const short* gB = Bb + (long)(n0 + (t >> 2)) * ldbt + (t & 3) * 8;
  char* lA = (char*)lds + wid * 1024;
  char* lB = (char*)lds + 8192 + wid * 1024;
  const long a64 = (long)64 * lda, b64s = (long)64 * ldbt;
  f32x4 acc[4][4];
#pragma unroll
  for (int m = 0; m < 4; ++m)
#pragma unroll
    for (int n = 0; n < 4; ++n) acc[m][n] = (f32x4){0.f, 0.f, 0.f, 0.f};

  int rsel = lane & 15, koff = (lane >> 4) * 16;
  for (int k = 0; k < Kd; k += 32) {
    gload16(gA, lA);
    gload16(gA + a64, lA + 4096);
    gload16(gB, lB);
    gload16(gB + b64s, lB + 4096);
    gA += 32; gB += 32;
    __syncthreads();
    bf16x8 af[4], bfr[4];
#pragma unroll
    for (int m = 0; m < 4; ++m)
      af[m] = *(const bf16x8*)((const char*)lds + (wr * 64 + m * 16 + rsel) * 64 + koff);
#pragma unroll
    for (int n = 0; n < 4; ++n)
      bfr[n] = *(const bf16x8*)((const char*)lds + 8192 + (wc * 64 + n * 16 + rsel) * 64 + koff);
#pragma unroll
    for (int m = 0; m < 4; ++m)
#pragma unroll
      for (int n = 0; n < 4; ++n)
        acc[m][n] = MFMA(af[m], bfr[n], acc[m][n]);
    __syncthreads();
  }

  int cl = lane & 15, rh = lane >> 4;
#pragma unroll
  for (int m = 0; m < 4; ++m) {
    int rgb = m0 + wr * 64 + m * 16 + rh * 4;
#pragma unroll
    for (int n = 0; n < 4; ++n) {
      int cg = n0 + wc * 64 + n * 16 + cl;
      f32x4 a = acc[m][n];
      if constexpr (EPI == EPI_QKV) {
        int sec = n0 >> 10;
        int cloc = cg & 1023;
        float bias = (sec == 0 ? b0 : sec == 1 ? b1 : b2)[cloc];
        if (sec == 0) {
#pragma unroll
          for (int r = 0; r < 4; ++r)
            o0[(size_t)(rgb + r) * 1024 + cloc] = f2bf(a[r] + bias);
        } else {
          short* dst = (sec == 1) ? o1 : o2;
          int bb = rgb >> 11, sl = rgb & 2047;
          s16x4 pk;
#pragma unroll
          for (int r = 0; r < 4; ++r) pk[r] = f2bf(a[r] + bias);
          *(s16x4*)(dst + ((long)bb * 1024 + cloc) * 2048 + sl) = pk;
        }
      } else if constexpr (EPI == EPI_KP) {
        short* dst = o0 + (long)bz * sC;
#pragma unroll
        for (int r = 0; r < 4; ++r)
          dst[(size_t)(rgb + r) * 1024 + cg] = f2bf(a[r] + b0[rgb + r]);
      } else if constexpr (EPI == EPI_VPT) {
        short* dst = o0 + (long)bz * sC;
        s16x4 pk;
#pragma unroll
        for (int r = 0; r < 4; ++r) pk[r] = f2bf(a[r] + b0[rgb + r]);
        *(s16x4*)(dst + (long)cg * 256 + rgb) = pk;
      } else if constexpr (EPI == EPI_RESID) {
        float bias = b0[cg];
#pragma unroll
        for (int r = 0; r < 4; ++r) {
          size_t idx = (size_t)(rgb + r) * 1024 + cg;
          fo[idx] = a[r] + bias + resid[idx];
        }
      } else if constexpr (EPI == EPI_GELU) {
        float bias = b0[cg];
#pragma unroll
        for (int r = 0; r < 4; ++r) {
          float xv = a[r] + bias;
          float g = 0.5f * xv * (1.f + erff(xv * 0.70710678118654752f));
          o0[(size_t)(rgb + r) * 4096 + cg] = f2bf(g);
        }
      }
    }
  }
}

// ---------------- fused Linformer attention ----------------
// grid (S/64, H, B), 256 thr. q[BS,1024] bf16, kp[B,256,1024], vpt[B,1024,256]
__global__ __launch_bounds__(256) void k_attn(
    const short* __restrict__ q, const short* __restrict__ kp,
    const short* __restrict__ vpt, short* __restrict__ oh) {
  int lane = threadIdx.x & 63, wid = threadIdx.x >> 6;
  int h = blockIdx.y, b = blockIdx.z;
  int s0 = blockIdx.x * 64 + wid * 16;
  int cl = lane & 15, rh = lane >> 4;
  __shared__ short plds[4][16][264];

  const short* qbase = q + ((size_t)(b * 2048 + s0 + cl)) * 1024 + h * 64 + rh * 8;
  bf16x8 qa0 = *(const bf16x8*)qbase;
  bf16x8 qa1 = *(const bf16x8*)(qbase + 32);

  f32x4 sc[16];
  const short* kb = kp + ((size_t)(b * 256 + cl)) * 1024 + h * 64 + rh * 8;
#pragma unroll
  for (int n = 0; n < 16; ++n) {
    const short* kn = kb + (size_t)(n * 16) * 1024;
    f32x4 a = (f32x4){0.f, 0.f, 0.f, 0.f};
    a = MFMA(qa0, *(const bf16x8*)kn, a);
    a = MFMA(qa1, *(const bf16x8*)(kn + 32), a);
    sc[n] = a * 0.125f;
  }

  float mx[4] = {-1e30f, -1e30f, -1e30f, -1e30f};
#pragma unroll
  for (int n = 0; n < 16; ++n)
#pragma unroll
    for (int r = 0; r < 4; ++r) mx[r] = fmaxf(mx[r], sc[n][r]);
#pragma unroll
  for (int o = 1; o < 16; o <<= 1)
#pragma unroll
    for (int r = 0; r < 4; ++r) mx[r] = fmaxf(mx[r], __shfl_xor(mx[r], o, 64));

  float sm[4] = {0.f, 0.f, 0.f, 0.f};
#pragma unroll
  for (int n = 0; n < 16; ++n)
#pragma unroll
    for (int r = 0; r < 4; ++r) {
      float e = expf(sc[n][r] - mx[r]);
      sc[n][r] = e;
      sm[r] += e;
    }
#pragma unroll
  for (int o = 1; o < 16; o <<= 1)
#pragma unroll
    for (int r = 0; r < 4; ++r) sm[r] += __shfl_xor(sm[r], o, 64);
  float inv[4];
#pragma unroll
  for (int r = 0; r < 4; ++r) inv[r] = 1.f / sm[r];

#pragma unroll
  for (int n = 0; n < 16; ++n)
#pragma unroll
    for (int r = 0; r < 4; ++r)
      plds[wid][rh * 4 + r][n * 16 + cl] = f2bf(sc[n][r] * inv[r]);
  asm volatile("s_waitcnt lgkmcnt(0)" ::: "memory");

  bf16x8 pa[8];
#pragma unroll
  for (int c = 0; c < 8; ++c)
    pa[c] = *(const bf16x8*)&plds[wid][cl][c * 32 + rh * 8];

  const short* vb = vpt + ((size_t)(b * 1024 + h * 64 + cl)) * 256 + rh * 8;
  short* ob = oh + ((size_t)(b * 2048 + s0 + rh * 4)) * 1024 + h * 64 + cl;
#pragma unroll
  for (int n = 0; n < 4; ++n) {
    f32x4 a = (f32x4){0.f, 0.f, 0.f, 0.f};
    const short* vn = vb + (size_t)(n * 16) * 256;
#pragma unroll
    for (int c = 0; c < 8; ++c)
      a = MFMA(pa[c], *(const bf16x8*)(vn + c * 32), a);
#pragma unroll
    for (int r = 0; r < 4; ++r)
      ob[(size_t)r * 1024 + n * 16] = f2bf(a[r]);
  }
}

// ---------------- host launch ----------------
extern "C" void kernel_launch(void* const* d_in, const int* in_sizes, int n_in,
                              void* d_out, int out_size, void* d_ws, size_t ws_size,
                              hipStream_t stream) {
  (void)in_sizes; (void)n_in; (void)out_size; (void)ws_size;
  const float* x    = (const float*)d_in[0];
  const float* z    = (const float*)d_in[1];
  const float* wq   = (const float*)d_in[2];
  const float* bq   = (const float*)d_in[3];
  const float* wk   = (const float*)d_in[4];
  const float* bk   = (const float*)d_in[5];
  const float* wv   = (const float*)d_in[6];
  const float* bv   = (const float*)d_in[7];
  const float* Ew   = (const float*)d_in[8];
  const float* Eb   = (const float*)d_in[9];
  const float* Fw   = (const float*)d_in[10];
  const float* Fb   = (const float*)d_in[11];
  const float* wo   = (const float*)d_in[12];
  const float* bo   = (const float*)d_in[13];
  const float* h1w  = (const float*)d_in[14];
  const float* h1b  = (const float*)d_in[15];
  const float* g1w  = (const float*)d_in[16];
  const float* g1b  = (const float*)d_in[17];
  const float* be1w = (const float*)d_in[18];
  const float* be1b = (const float*)d_in[19];
  const float* h2w  = (const float*)d_in[20];
  const float* h2b  = (const float*)d_in[21];
  const float* g2w  = (const float*)d_in[22];
  const float* g2b  = (const float*)d_in[23];
  const float* be2w = (const float*)d_in[24];
  const float* be2b = (const float*)d_in[25];
  const float* m1w  = (const float*)d_in[26];
  const float* m1b  = (const float*)d_in[27];
  const float* m2w  = (const float*)d_in[28];
  const float* m2b  = (const float*)d_in[29];
  float* out = (float*)d_out;

  char* ws = (char*)d_ws;
  size_t off = 0;
  auto alloc = [&](size_t bytes) {
    char* p = ws + off;
    off += (bytes + 255) & ~(size_t)255;
    return p;
  };
  // Workspace plan (total ~194.3 MB; previous round's 270.7 MB likely
  // overflowed a 256 MB ws -> VM fault -> queue hang):
  short* x1  = (short*)alloc((size_t)32 << 20);  // [0,32)
  short* qb  = (short*)alloc((size_t)32 << 20);  // [32,64)
  short* kT  = (short*)alloc((size_t)32 << 20);  // [64,96)
  short* vT  = (short*)alloc((size_t)32 << 20);  // [96,128)
  short* ah  = (short*)alloc((size_t)32 << 20);  // [128,160)
  short* kpj = (short*)alloc((size_t)4 << 20);
  short* vpt = (short*)alloc((size_t)4 << 20);
  short* wqkvT = (short*)alloc((size_t)3072 * 1024 * 2);
  short* woT   = (short*)alloc((size_t)1024 * 1024 * 2);
  short* m1T   = (short*)alloc((size_t)4096 * 1024 * 2);
  short* m2T   = (short*)alloc((size_t)1024 * 4096 * 2);
  short* EwT   = (short*)alloc((size_t)256 * 2048 * 2);
  short* FwT   = (short*)alloc((size_t)256 * 2048 * 2);
  float* hbuf  = (float*)alloc((size_t)2 * 8 * 1024 * 4);
  float* sobuf = (float*)alloc((size_t)4 * 8 * 1024 * 4);
  // aliases (lifetime-disjoint):
  float* aout = (float*)kT;   // 64 MB over kT+vT, live after Linformer projections
  short* x2   = ah;           // live after Wo gemm consumed ah
  short* hmid = x1;           // 64 MB over x1+qb, chunk buffer for MLP

  dim3 blk(256);
  // weight conversions
  k_transpose_cvt<<<dim3(16, 16), blk, 0, stream>>>(wq, wqkvT, 1024, 1024);
  k_transpose_cvt<<<dim3(16, 16), blk, 0, stream>>>(wk, wqkvT + 1024 * 1024, 1024, 1024);
  k_transpose_cvt<<<dim3(16, 16), blk, 0, stream>>>(wv, wqkvT + 2 * 1024 * 1024, 1024, 1024);
  k_transpose_cvt<<<dim3(16, 16), blk, 0, stream>>>(wo, woT, 1024, 1024);
  k_transpose_cvt<<<dim3(64, 16), blk, 0, stream>>>(m1w, m1T, 1024, 4096);
  k_transpose_cvt<<<dim3(16, 64), blk, 0, stream>>>(m2w, m2T, 4096, 1024);
  k_transpose_cvt<<<dim3(4, 32), blk, 0, stream>>>(Ew, EwT, 2048, 256);
  k_transpose_cvt<<<dim3(4, 32), blk, 0, stream>>>(Fw, FwT, 2048, 256);
  // conditioning
  k_cond_h<<<dim3(16, 8, 2), blk, 0, stream>>>(z, h1w, h1b, h2w, h2b, hbuf);
  k_cond_so<<<dim3(16, 8, 4), blk, 0, stream>>>(hbuf, g1w, g1b, be1w, be1b,
                                                g2w, g2b, be2w, be2b, sobuf);
  // adaLN1 -> x1 (bf16)
  k_adaln<<<dim3(16384), blk, 0, stream>>>(x, sobuf, 0, x1);
  // QKV: q normal, k/v transposed per-batch
  k_gemm<EPI_QKV><<<dim3(24, 128, 1), blk, 0, stream>>>(
      x1, 0, 1024, wqkvT, 0, 1024, 1024,
      qb, kT, vT, bq, bk, bv, nullptr, nullptr, 0);
  // Linformer projections
  k_gemm<EPI_KP><<<dim3(8, 2, 8), blk, 0, stream>>>(
      EwT, 0, 2048, kT, (long)1024 * 2048, 2048, 2048,
      kpj, nullptr, nullptr, Eb, nullptr, nullptr, nullptr, nullptr, 262144);
  k_gemm<EPI_VPT><<<dim3(8, 2, 8), blk, 0, stream>>>(
      FwT, 0, 2048, vT, (long)1024 * 2048, 2048, 2048,
      vpt, nullptr, nullptr, Fb, nullptr, nullptr, nullptr, nullptr, 262144);
  // attention (kT/vT now dead -> aout alias region free)
  k_attn<<<dim3(32, 16, 8), blk, 0, stream>>>(qb, kpj, vpt, ah);
  // Wo + bias + residual(x) -> attn_out fp32 (into kT/vT region)
  k_gemm<EPI_RESID><<<dim3(8, 128, 1), blk, 0, stream>>>(
      ah, 0, 1024, woT, 0, 1024, 1024,
      nullptr, nullptr, nullptr, bo, nullptr, nullptr, x, aout, 0);
  // adaLN2 -> x2 (bf16, into ah region; ah dead after Wo gemm)
  k_adaln<<<dim3(16384), blk, 0, stream>>>(aout, sobuf, 1, x2);
  // MLP in 2 chunks of 8192 rows; hmid chunk buffer overlays x1+qb (dead)
  for (int c = 0; c < 2; ++c) {
    const short* x2c = x2 + (size_t)c * 8192 * 1024;
    const float* aoc = aout + (size_t)c * 8192 * 1024;
    float* outc = out + (size_t)c * 8192 * 1024;
    k_gemm<EPI_GELU><<<dim3(32, 64, 1), blk, 0, stream>>>(
        x2c, 0, 1024, m1T, 0, 1024, 1024,
        hmid, nullptr, nullptr, m1b, nullptr, nullptr, nullptr, nullptr, 0);
    k_gemm<EPI_RESID><<<dim3(8, 64, 1), blk, 0, stream>>>(
        hmid, 0, 4096, m2T, 0, 4096, 4096,
        nullptr, nullptr, nullptr, m2b, nullptr, nullptr, aoc, outc, 0);
  }
}